// Round 11
// baseline (204.123 us; speedup 1.0000x reference)
//
#include <hip/hip_runtime.h>
#include <math.h>

#define EPS_F 1e-6f

typedef __attribute__((ext_vector_type(8))) short short8;
typedef __attribute__((ext_vector_type(4))) float f32x4;
typedef unsigned long long ull;

static __device__ __forceinline__ unsigned short f2bf(float f) {
    unsigned u = __float_as_uint(f);
    u += 0x7fff + ((u >> 16) & 1);          // round-to-nearest-even
    return (unsigned short)(u >> 16);
}
static __device__ __forceinline__ ull pack4(float a, float b, float c, float d) {
    return (ull)f2bf(a) | ((ull)f2bf(b) << 16) | ((ull)f2bf(c) << 32) | ((ull)f2bf(d) << 48);
}
static __device__ __forceinline__ float bf2f(unsigned short s) {
    return __uint_as_float(((unsigned)s) << 16);
}

// ---------------- small kernels ----------------

__global__ void kff(const float* __restrict__ F, float* __restrict__ FF) {
    int i = blockIdx.x, j = threadIdx.x;
    float s = 0.f;
    for (int k = 0; k < 128; ++k) s += F[k*128 + i] * F[k*128 + j];
    FF[i*128 + j] = s;
}

__global__ void knorm(const float* __restrict__ FF, float* __restrict__ inv) {
    float s = 0.f;
    for (int idx = threadIdx.x; idx < 128*128; idx += 256) { float v = FF[idx]; s += v*v; }
    for (int o = 32; o > 0; o >>= 1) s += __shfl_down(s, o);
    __shared__ float wsum[4];
    int lane = threadIdx.x & 63, w = threadIdx.x >> 6;
    if (lane == 0) wsum[w] = s;
    __syncthreads();
    if (threadIdx.x == 0) inv[0] = 1.f / (sqrtf(wsum[0]+wsum[1]+wsum[2]+wsum[3]) + EPS_F);
}

// X (f32, 1M elems) -> bf16
__global__ void kxbf(const float* __restrict__ X, short* __restrict__ Xb) {
    int i = blockIdx.x*blockDim.x + threadIdx.x;    // group of 8
    const float4* p = (const float4*)(X + (size_t)i*8);
    float4 v0 = p[0], v1 = p[1];
    *(ull*)&Xb[(size_t)i*8    ] = pack4(v0.x, v0.y, v0.z, v0.w);
    *(ull*)&Xb[(size_t)i*8 + 4] = pack4(v1.x, v1.y, v1.z, v1.w);
}

// ---------------- GEMM1: Yp[split] = Xb(bf16) @ Q(f32); co-writes Qb = bf16(Q) ------
// BM=128 BN=64 BK=32, 512 thr (8 waves 4m x 2n), split-K=8, non-atomic partials.
__global__ __launch_bounds__(512) void gemm1(
    const short* __restrict__ Xb, const float* __restrict__ Qg,
    short* __restrict__ Qb, float* __restrict__ Yp, int N, int K, int KC)
{
    constexpr int LDT = 40;                 // shorts/row: 32 data + 8 pad (80 B)
    __shared__ short As[2][128 * LDT];
    __shared__ short Bs[2][64 * LDT];

    const int t    = threadIdx.x;
    const int lane = t & 63;
    const int w    = t >> 6;
    const int wm   = (w >> 1) * 32;
    const int wn   = (w & 1)  * 32;
    const int l16  = lane & 15;
    const int lq   = lane >> 4;
    const int n0   = blockIdx.x * 64;
    const int kb   = blockIdx.y * KC;
    const int NS   = KC >> 5;

    float* Cout = Yp + (size_t)blockIdx.y * (128 * 8192);

    const int ar0 = t >> 2, ako = (t & 3) * 8;      // A: one short8/thread
    const int bn  = t & 63, bkq = t >> 6;           // B: col bn, row-quad bkq (4 rows)

    f32x4 acc[2][2];
    #pragma unroll
    for (int i = 0; i < 2; ++i) { acc[i][0] = (f32x4){0,0,0,0}; acc[i][1] = (f32x4){0,0,0,0}; }

    short8 sa;
    float  sbt[4];

#define G1_LOAD(k0) do {                                                          \
        sa = *(const short8*)&Xb[(size_t)ar0*K + (k0) + ako];                     \
        _Pragma("unroll")                                                         \
        for (int j = 0; j < 4; ++j)                                               \
            sbt[j] = Qg[(size_t)((k0) + bkq*4 + j)*N + n0 + bn];                  \
    } while (0)

#define G1_WRITE(buf, k0w) do {                                                   \
        *(short8*)&As[buf][ar0*LDT + ako] = sa;                                   \
        unsigned short q0 = f2bf(sbt[0]), q1 = f2bf(sbt[1]);                      \
        unsigned short q2 = f2bf(sbt[2]), q3 = f2bf(sbt[3]);                      \
        *(ull*)&Bs[buf][bn*LDT + bkq*4] =                                         \
            (ull)q0 | ((ull)q1 << 16) | ((ull)q2 << 32) | ((ull)q3 << 48);        \
        Qb[(size_t)((k0w) + bkq*4 + 0)*N + n0 + bn] = (short)q0;                  \
        Qb[(size_t)((k0w) + bkq*4 + 1)*N + n0 + bn] = (short)q1;                  \
        Qb[(size_t)((k0w) + bkq*4 + 2)*N + n0 + bn] = (short)q2;                  \
        Qb[(size_t)((k0w) + bkq*4 + 3)*N + n0 + bn] = (short)q3;                  \
    } while (0)

#define G1_MFMA(buf) do {                                                         \
        short8 af[2], bfr[2];                                                     \
        _Pragma("unroll")                                                         \
        for (int mt = 0; mt < 2; ++mt)                                            \
            af[mt] = *(const short8*)&As[buf][(wm + mt*16 + l16)*LDT + lq*8];     \
        _Pragma("unroll")                                                         \
        for (int nt = 0; nt < 2; ++nt)                                            \
            bfr[nt] = *(const short8*)&Bs[buf][(wn + nt*16 + l16)*LDT + lq*8];    \
        _Pragma("unroll")                                                         \
        for (int mt = 0; mt < 2; ++mt) {                                          \
            acc[mt][0] = __builtin_amdgcn_mfma_f32_16x16x32_bf16(af[mt], bfr[0], acc[mt][0], 0, 0, 0); \
            acc[mt][1] = __builtin_amdgcn_mfma_f32_16x16x32_bf16(af[mt], bfr[1], acc[mt][1], 0, 0, 0); \
        }                                                                         \
    } while (0)

    G1_LOAD(kb);
    G1_WRITE(0, kb);
    __syncthreads();

    for (int ks = 0; ks < NS; ++ks) {
        const int cur = ks & 1;
        const bool more = (ks + 1 < NS);
        const int knext = kb + (ks + 1) * 32;
        if (more) G1_LOAD(knext);
        G1_MFMA(cur);
        if (more) G1_WRITE(cur ^ 1, knext);
        __syncthreads();
    }

#undef G1_LOAD
#undef G1_WRITE
#undef G1_MFMA

    #pragma unroll
    for (int mt = 0; mt < 2; ++mt)
        #pragma unroll
        for (int nt = 0; nt < 2; ++nt)
            #pragma unroll
            for (int r = 0; r < 4; ++r)
                Cout[(size_t)(wm + mt*16 + lq*4 + r)*N + n0 + wn + nt*16 + l16] = acc[mt][nt][r];
}

// ---------------- GEMM2: Zp[split] = Rg(bf16) @ Qb(bf16 rows), pure-copy staging -----
__global__ __launch_bounds__(512) void gemm2(
    const short* __restrict__ Rg, const short* __restrict__ Qb,
    float* __restrict__ Zp, int N, int K, int KC)
{
    constexpr int LDT = 40;
    __shared__ short As[2][128 * LDT];
    __shared__ short Bs[2][64 * LDT];

    const int t    = threadIdx.x;
    const int lane = t & 63;
    const int w    = t >> 6;
    const int wm   = (w >> 1) * 32;
    const int wn   = (w & 1)  * 32;
    const int l16  = lane & 15;
    const int lq   = lane >> 4;
    const int n0   = blockIdx.x * 64;
    const int kb   = blockIdx.y * KC;
    const int NS   = KC >> 5;

    float* Cout = Zp + (size_t)blockIdx.y * (128 * 8192);

    const int ar0 = t >> 2, ako = (t & 3) * 8;      // A: one short8/thread (all 512)
    const int bi  = t >> 2, bjo = (t & 3) * 8;      // B (t<256): row n0+bi, j-offset

    f32x4 acc[2][2];
    #pragma unroll
    for (int i = 0; i < 2; ++i) { acc[i][0] = (f32x4){0,0,0,0}; acc[i][1] = (f32x4){0,0,0,0}; }

    short8 sa, sb8;

#define G2_LOAD(k0) do {                                                          \
        sa = *(const short8*)&Rg[(size_t)ar0*K + (k0) + ako];                     \
        if (t < 256)                                                              \
            sb8 = *(const short8*)&Qb[(size_t)(n0 + bi)*K + (k0) + bjo];          \
    } while (0)

#define G2_WRITE(buf) do {                                                        \
        *(short8*)&As[buf][ar0*LDT + ako] = sa;                                   \
        if (t < 256)                                                              \
            *(short8*)&Bs[buf][bi*LDT + bjo] = sb8;                               \
    } while (0)

#define G2_MFMA(buf) do {                                                         \
        short8 af[2], bfr[2];                                                     \
        _Pragma("unroll")                                                         \
        for (int mt = 0; mt < 2; ++mt)                                            \
            af[mt] = *(const short8*)&As[buf][(wm + mt*16 + l16)*LDT + lq*8];     \
        _Pragma("unroll")                                                         \
        for (int nt = 0; nt < 2; ++nt)                                            \
            bfr[nt] = *(const short8*)&Bs[buf][(wn + nt*16 + l16)*LDT + lq*8];    \
        _Pragma("unroll")                                                         \
        for (int mt = 0; mt < 2; ++mt) {                                          \
            acc[mt][0] = __builtin_amdgcn_mfma_f32_16x16x32_bf16(af[mt], bfr[0], acc[mt][0], 0, 0, 0); \
            acc[mt][1] = __builtin_amdgcn_mfma_f32_16x16x32_bf16(af[mt], bfr[1], acc[mt][1], 0, 0, 0); \
        }                                                                         \
    } while (0)

    G2_LOAD(kb);
    G2_WRITE(0);
    __syncthreads();

    for (int ks = 0; ks < NS; ++ks) {
        const int cur = ks & 1;
        const bool more = (ks + 1 < NS);
        if (more) G2_LOAD(kb + (ks + 1) * 32);
        G2_MFMA(cur);
        if (more) G2_WRITE(cur ^ 1);
        __syncthreads();
    }

#undef G2_LOAD
#undef G2_WRITE
#undef G2_MFMA

    #pragma unroll
    for (int mt = 0; mt < 2; ++mt)
        #pragma unroll
        for (int nt = 0; nt < 2; ++nt)
            #pragma unroll
            for (int r = 0; r < 4; ++r)
                Cout[(size_t)(wm + mt*16 + lq*4 + r)*N + n0 + wn + nt*16 + l16] = acc[mt][nt][r];
}

// ---------------- fused Horner (reduces GEMM1 partials, emits bf16 R k-major) ---------
__global__ __launch_bounds__(512) void horner_fused(
    const float* __restrict__ FF, const float* __restrict__ invn,
    const float* __restrict__ lam, const float* __restrict__ gam,
    const float* __restrict__ Yp, short* __restrict__ Rg, int N)
{
    constexpr int LDT = 136;
    constexpr int T = 14;
    constexpr int SPL = 8;
    __shared__ short Abf[128 * LDT];        // [m][k]
    __shared__ short Rs[32 * LDT];          // [j_local][m]

    const int t    = threadIdx.x;
    const int lane = t & 63;
    const int w    = t >> 6;
    const int wm   = (w >> 1) * 32;
    const int wn   = (w & 1) * 16;
    const int l16  = lane & 15;
    const int lq   = lane >> 4;
    const int j0   = blockIdx.x * 32;

    #pragma unroll
    for (int i = 0; i < 8; ++i) {
        int flat = t + i*512;
        int m = flat >> 5, k4 = flat & 31;
        float4 v = *(const float4*)&FF[m*128 + k4*4];
        *(ull*)&Abf[m*LDT + k4*4] = pack4(v.x, v.y, v.z, v.w);
    }
    {
        int j = t & 31, mg = t >> 5;
        float vv[8];
        #pragma unroll
        for (int r2 = 0; r2 < 8; ++r2) {
            size_t idx = (size_t)(mg*8 + r2)*N + j0 + j;
            float s = 0.f;
            #pragma unroll
            for (int sp = 0; sp < SPL; ++sp) s += Yp[(size_t)sp*(128*8192) + idx];
            vv[r2] = s;
        }
        *(ull*)&Rs[j*LDT + mg*8    ] = pack4(vv[0], vv[1], vv[2], vv[3]);
        *(ull*)&Rs[j*LDT + mg*8 + 4] = pack4(vv[4], vv[5], vv[6], vv[7]);
    }
    __syncthreads();

    const int col = j0 + wn + l16;
    float yreg[2][4];
    #pragma unroll
    for (int mt = 0; mt < 2; ++mt)
        #pragma unroll
        for (int r = 0; r < 4; ++r)
            yreg[mt][r] = bf2f((unsigned short)Rs[(wn + l16)*LDT + wm + mt*16 + lq*4 + r]);
    const float s = gam[0] * lam[col] * invn[0];

    for (int it = 0; it < T; ++it) {
        f32x4 racc[2];
        racc[0] = (f32x4){0,0,0,0};
        racc[1] = (f32x4){0,0,0,0};
        #pragma unroll
        for (int kq = 0; kq < 4; ++kq) {
            short8 b  = *(const short8*)&Rs[(wn + l16)*LDT + kq*32 + lq*8];
            short8 a0 = *(const short8*)&Abf[(wm      + l16)*LDT + kq*32 + lq*8];
            short8 a1 = *(const short8*)&Abf[(wm + 16 + l16)*LDT + kq*32 + lq*8];
            racc[0] = __builtin_amdgcn_mfma_f32_16x16x32_bf16(a0, b, racc[0], 0, 0, 0);
            racc[1] = __builtin_amdgcn_mfma_f32_16x16x32_bf16(a1, b, racc[1], 0, 0, 0);
        }
        __syncthreads();
        #pragma unroll
        for (int mt = 0; mt < 2; ++mt) {
            float r0 = yreg[mt][0] + s*racc[mt][0];
            float r1 = yreg[mt][1] + s*racc[mt][1];
            float r2 = yreg[mt][2] + s*racc[mt][2];
            float r3 = yreg[mt][3] + s*racc[mt][3];
            if (it < T-1) {
                *(ull*)&Rs[(wn + l16)*LDT + wm + mt*16 + lq*4] = pack4(r0, r1, r2, r3);
            } else {
                int row = wm + mt*16 + lq*4;
                Rg[(size_t)(row+0)*N + col] = (short)f2bf(r0);
                Rg[(size_t)(row+1)*N + col] = (short)f2bf(r1);
                Rg[(size_t)(row+2)*N + col] = (short)f2bf(r2);
                Rg[(size_t)(row+3)*N + col] = (short)f2bf(r3);
            }
        }
        if (it < T-1) __syncthreads();
    }
}

// ---------------- Z = sum of 8 split partials ----------------
__global__ __launch_bounds__(256) void zred(const float* __restrict__ Zp,
                                            float* __restrict__ Z) {
    int i = (blockIdx.x*blockDim.x + threadIdx.x) * 4;
    f32x4 s = (f32x4){0,0,0,0};
    #pragma unroll
    for (int sp = 0; sp < 8; ++sp) {
        const float4 v = *(const float4*)&Zp[(size_t)sp*(128*8192) + i];
        s[0] += v.x; s[1] += v.y; s[2] += v.z; s[3] += v.w;
    }
    *(f32x4*)&Z[i] = s;
}

// ---------------- launch ----------------

extern "C" void kernel_launch(void* const* d_in, const int* in_sizes, int n_in,
                              void* d_out, int out_size, void* d_ws, size_t ws_size,
                              hipStream_t stream) {
    const float* X   = (const float*)d_in[0];   // 128 x 8192
    const float* F   = (const float*)d_in[1];   // 128 x 128
    const float* Q   = (const float*)d_in[2];   // 8192 x 8192
    const float* lam = (const float*)d_in[3];   // 8192
    const float* gam = (const float*)d_in[4];   // 1
    float* Z = (float*)d_out;                   // 128 x 8192 (f32)

    const int N = 8192, K = 8192;

    char* ws = (char*)d_ws;
    float* FF  = (float*)(ws);                               // 64 KB
    float* inv = (float*)(ws + 65536);                       // 4 B
    short* Xb  = (short*)(ws + 131072);                      // 2 MB
    short* Rg  = (short*)(ws + 2228224);                     // 2 MB
    float* Yp  = (float*)(ws + 4325376);                     // 8 x 4 MB
    float* Zp  = (float*)(ws + 4325376 + 33554432);          // 8 x 4 MB
    short* Qb  = (short*)(ws + 4325376 + 67108864);          // 128 MB bf16 Q

    hipLaunchKernelGGL(kff,   dim3(128), dim3(128), 0, stream, F, FF);
    hipLaunchKernelGGL(knorm, dim3(1),   dim3(256), 0, stream, FF, inv);
    hipLaunchKernelGGL(kxbf,  dim3(512), dim3(256), 0, stream, X, Xb);

    // GEMM1: Yp[s] = Xb @ Q (f32), co-writes Qb = bf16(Q)
    hipLaunchKernelGGL(gemm1, dim3(128, 8), dim3(512), 0, stream,
                       Xb, Q, Qb, Yp, N, K, 1024);

    // fused Horner: reduce 8 partials, Neumann series, emit bf16 R (k-major)
    hipLaunchKernelGGL(horner_fused, dim3(256), dim3(512), 0, stream,
                       FF, inv, lam, gam, Yp, Rg, N);

    // GEMM2: Zp[s] = Rg @ Qb rows (half the bytes, pure-copy staging)
    hipLaunchKernelGGL(gemm2, dim3(128, 8), dim3(512), 0, stream,
                       Rg, Qb, Zp, N, K, 1024);

    // Z = sum_s Zp[s]
    hipLaunchKernelGGL(zred, dim3(1024), dim3(256), 0, stream, Zp, Z);
}